// Round 3
// baseline (90.035 us; speedup 1.0000x reference)
//
#include <hip/hip_runtime.h>

// Per-channel color-temperature scale: out[b,c,h,w] = in[b,c,h,w] * cm[c]
// cm = {255, 236, 224} / 255, imgs (64,3,512,512) fp32 NCHW.
//
// R3 discriminating experiment: non-temporal on BOTH load and store — pure
// HBM stream, zero L3 allocation either direction. If R2's partial L3
// read-residency was real, this regresses (keep R2). If we were already at
// the mixed full-HBM roofline, this matches or slightly beats it (less cache
// pollution / probe overhead).

typedef float vf4 __attribute__((ext_vector_type(4)));

__global__ __launch_bounds__(256) void RandomAdjustTemp_kernel(
    const vf4* __restrict__ in, vf4* __restrict__ out, int n4) {
    const float cm1 = 236.0f / 255.0f;
    const float cm2 = 224.0f / 255.0f;
    const int stride = gridDim.x * blockDim.x;
    #pragma unroll 8
    for (int i = blockIdx.x * blockDim.x + threadIdx.x; i < n4; i += stride) {
        const int ch = (i >> 16) % 3;          // 65536 float4 per channel plane
        const float m = (ch == 0) ? 1.0f : (ch == 1 ? cm1 : cm2);
        vf4 v = __builtin_nontemporal_load(&in[i]);   // stream reads past L3
        v *= m;
        __builtin_nontemporal_store(v, &out[i]);      // stream writes past L3
    }
}

extern "C" void kernel_launch(void* const* d_in, const int* in_sizes, int n_in,
                              void* d_out, int out_size, void* d_ws, size_t ws_size,
                              hipStream_t stream) {
    const vf4* in = (const vf4*)d_in[0];
    vf4* out = (vf4*)d_out;
    const int n = in_sizes[0];          // 50,331,648 (divisible by 4)
    const int n4 = n >> 2;              // 12,582,912 float4s
    const int block = 256;
    int grid = (n4 + block - 1) / block;
    if (grid > 2048) grid = 2048;       // 8 blocks/CU, 32 waves/CU
    RandomAdjustTemp_kernel<<<grid, block, 0, stream>>>(in, out, n4);
}

// Round 4
// 59.911 us; speedup vs baseline: 1.5028x; 1.5028x over previous
//
#include <hip/hip_runtime.h>

// Per-channel color-temperature scale: out[b,c,h,w] = in[b,c,h,w] * cm[c]
// cm = {255, 236, 224} / 255, imgs (64,3,512,512) fp32 NCHW.
//
// R4: fill-kernel-shaped dispatch — flat one float4 per thread, no loop.
// Data path kept from R2 (winner): cacheable load (input L3-resident across
// graph replays) + non-temporal store (write stream bypasses L3, doesn't
// evict the input). The harness's fillBuffer kernels hit 7 TB/s with this
// short-lived-wave shape; testing whether the dispatch shape (not the data
// path) is what separates us from them.

typedef float vf4 __attribute__((ext_vector_type(4)));

__global__ __launch_bounds__(256) void RandomAdjustTemp_kernel(
    const vf4* __restrict__ in, vf4* __restrict__ out, int n4) {
    const int i = blockIdx.x * blockDim.x + threadIdx.x;
    if (i >= n4) return;
    const float cm1 = 236.0f / 255.0f;
    const float cm2 = 224.0f / 255.0f;
    const int ch = (i >> 16) % 3;              // 65536 float4 per channel plane
    const float m = (ch == 0) ? 1.0f : (ch == 1 ? cm1 : cm2);
    vf4 v = in[i];                             // cacheable: L3 keeps input
    v *= m;
    __builtin_nontemporal_store(v, &out[i]);   // nt: bypass L3 on writes
}

extern "C" void kernel_launch(void* const* d_in, const int* in_sizes, int n_in,
                              void* d_out, int out_size, void* d_ws, size_t ws_size,
                              hipStream_t stream) {
    const vf4* in = (const vf4*)d_in[0];
    vf4* out = (vf4*)d_out;
    const int n = in_sizes[0];          // 50,331,648 (divisible by 4)
    const int n4 = n >> 2;              // 12,582,912 float4s
    const int block = 256;
    const int grid = (n4 + block - 1) / block;  // 49,152 blocks, one-shot
    RandomAdjustTemp_kernel<<<grid, block, 0, stream>>>(in, out, n4);
}